// Round 2
// baseline (245550.781 us; speedup 1.0000x reference)
//
#include <hip/hip_runtime.h>
#include <hip/hip_bf16.h>

#define TT 8192
#define BB 16
#define DD 7
#define HH 256

typedef unsigned short u16;
typedef unsigned int   u32;

// ---------------- workspace layout ----------------
// wpk0: u16[132*256*8]  layer0 weights, rows 264: r<7 -> Wih0 col r, 7..262 -> Whh0 col r-7, 263 -> 0
//        flat idx = (k2*256 + j)*8 + q*2 + p, value = W[gate q*256+j][row 2*k2+p]
// wpk1: u16[256*256*8]  layer1 weights, rows 512: r<256 -> Wih1 col r, else Whh1 col r-256
// b0pk: float[1024]  b0pk[j*4+q] = b0[q*256+j]
// b1pk: float[1024]
// y0  : u16[TT*BB*HH] bf16 layer-0 outputs
static const size_t N_W0   = 132u*256u*8u;   // 270336
static const size_t N_W1   = 256u*256u*8u;   // 524288
static const size_t OFF_W0 = 0;
static const size_t OFF_W1 = OFF_W0 + N_W0*sizeof(u16);       // 540672
static const size_t OFF_B0 = OFF_W1 + N_W1*sizeof(u16);       // 1589248
static const size_t OFF_B1 = OFF_B0 + 1024*sizeof(float);     // 1593344
static const size_t OFF_Y0 = OFF_B1 + 1024*sizeof(float);     // 1597440

__device__ __forceinline__ float blo(u32 u){ return __uint_as_float(u << 16); }
__device__ __forceinline__ float bhi(u32 u){ return __uint_as_float(u & 0xffff0000u); }
__device__ __forceinline__ float sigf(float x){ return 1.0f/(1.0f + __expf(-x)); }
__device__ __forceinline__ float tanhf_(float x){ return 1.0f - 2.0f/(__expf(2.0f*x) + 1.0f); }
__device__ __forceinline__ u16 f2bf(float v){
  union { __hip_bfloat16 b; u16 s; } u; u.b = __float2bfloat16(v); return u.s;
}

__global__ __launch_bounds__(256) void pack_kernel(
    const float* __restrict__ Wih0, const float* __restrict__ Whh0, const float* __restrict__ b0,
    const float* __restrict__ Wih1, const float* __restrict__ Whh1, const float* __restrict__ b1,
    u16* __restrict__ wpk0, u16* __restrict__ wpk1,
    float* __restrict__ b0pk, float* __restrict__ b1pk) {
  int idx = blockIdx.x*256 + threadIdx.x;
  const int n0 = 132*2048, n1 = 256*2048;
  if (idx < n0) {
    int k2 = idx >> 11, rem = idx & 2047;
    int j = rem >> 3, qq = rem & 7, q = qq >> 1, p = qq & 1;
    int r = 2*k2 + p, G = q*256 + j;
    float v = 0.0f;
    if (r < 7)        v = Wih0[G*7 + r];
    else if (r < 263) v = Whh0[G*256 + (r-7)];
    wpk0[idx] = f2bf(v);
  } else if (idx < n0 + n1) {
    int i2 = idx - n0;
    int k2 = i2 >> 11, rem = i2 & 2047;
    int j = rem >> 3, qq = rem & 7, q = qq >> 1, p = qq & 1;
    int r = 2*k2 + p, G = q*256 + j;
    float v = (r < 256) ? Wih1[G*256 + r] : Whh1[G*256 + (r-256)];
    wpk1[i2] = f2bf(v);
  } else if (idx < n0 + n1 + 1024) {
    int i3 = idx - n0 - n1;
    int j = i3 >> 2, q = i3 & 3;
    b0pk[i3] = b0[q*256 + j];
  } else if (idx < n0 + n1 + 2048) {
    int i3 = idx - n0 - n1 - 1024;
    int j = i3 >> 2, q = i3 & 3;
    b1pk[i3] = b1[q*256 + j];
  }
}

// One block per batch element. Thread j owns hidden unit j (all 4 gates).
__global__ __launch_bounds__(256) void lstm_l0(
    const float* __restrict__ x, const uint4* __restrict__ w,
    const float4* __restrict__ bpk, u16* __restrict__ y0,
    float* __restrict__ dout) {
  const int b = blockIdx.x, j = threadIdx.x;
  __shared__ __align__(16) float vec[264];   // [0..6]=x_t, [7..262]=h, [263]=0
  const float4 bias = bpk[j];
  float c = 0.0f, h = 0.0f;
  vec[7 + j] = 0.0f;
  if (j < DD) vec[j] = x[(size_t)b*TT*DD + j];
  if (j == 255) vec[263] = 0.0f;
  __syncthreads();
  const float4* vec4 = reinterpret_cast<const float4*>(vec);
  for (int t = 0; t < TT; ++t) {
    float xn = 0.0f;
    if (j < DD && t + 1 < TT) xn = x[((size_t)b*TT + t + 1)*DD + j];
    float4 acc = bias;
    #pragma unroll 6
    for (int k4 = 0; k4 < 66; ++k4) {
      const float4 h4 = vec4[k4];
      const uint4 wA = w[(2*k4 + 0)*256 + j];
      const uint4 wB = w[(2*k4 + 1)*256 + j];
      acc.x += blo(wA.x)*h4.x + bhi(wA.x)*h4.y + blo(wB.x)*h4.z + bhi(wB.x)*h4.w;
      acc.y += blo(wA.y)*h4.x + bhi(wA.y)*h4.y + blo(wB.y)*h4.z + bhi(wB.y)*h4.w;
      acc.z += blo(wA.z)*h4.x + bhi(wA.z)*h4.y + blo(wB.z)*h4.z + bhi(wB.z)*h4.w;
      acc.w += blo(wA.w)*h4.x + bhi(wA.w)*h4.y + blo(wB.w)*h4.z + bhi(wB.w)*h4.w;
    }
    const float ig = sigf(acc.x), fg = sigf(acc.y);
    const float gg = tanhf_(acc.z), og = sigf(acc.w);
    c = fg*c + ig*gg;
    h = og*tanhf_(c);
    y0[((size_t)t*BB + b)*HH + j] = f2bf(h);
    __syncthreads();
    vec[7 + j] = h;
    if (j < DD) vec[j] = xn;
    __syncthreads();
  }
  dout[917504 + b*HH + j] = h;   // h_n[0][b][j]
  dout[925696 + b*HH + j] = c;   // c_n[0][b][j]
}

// Layer 1 + fused head. vec = [y0_t (256), h1 (256)].
__global__ __launch_bounds__(256) void lstm_l1(
    const u16* __restrict__ y0, const uint4* __restrict__ w,
    const float4* __restrict__ bpk, const float* __restrict__ Whead,
    const float* __restrict__ bhead, float* __restrict__ dout) {
  const int b = blockIdx.x, j = threadIdx.x;
  __shared__ __align__(16) float vec[512];
  __shared__ float hd[7][4];
  const float4 bias = bpk[j];
  float wh[7];
  #pragma unroll
  for (int o = 0; o < 7; ++o) wh[o] = Whead[o*HH + j];
  const float bh = (j < DD) ? bhead[j] : 0.0f;
  float c = 0.0f, h = 0.0f;
  vec[256 + j] = 0.0f;
  vec[j] = blo((u32)y0[(size_t)b*HH + j]);
  __syncthreads();
  const float4* vec4 = reinterpret_cast<const float4*>(vec);
  const int lane = j & 63, wv = j >> 6;
  for (int t = 0; t < TT; ++t) {
    u32 yn = 0;
    if (t + 1 < TT) yn = (u32)y0[((size_t)(t+1)*BB + b)*HH + j];
    float4 acc = bias;
    #pragma unroll 8
    for (int k4 = 0; k4 < 128; ++k4) {
      const float4 h4 = vec4[k4];
      const uint4 wA = w[(2*k4 + 0)*256 + j];
      const uint4 wB = w[(2*k4 + 1)*256 + j];
      acc.x += blo(wA.x)*h4.x + bhi(wA.x)*h4.y + blo(wB.x)*h4.z + bhi(wB.x)*h4.w;
      acc.y += blo(wA.y)*h4.x + bhi(wA.y)*h4.y + blo(wB.y)*h4.z + bhi(wB.y)*h4.w;
      acc.z += blo(wA.z)*h4.x + bhi(wA.z)*h4.y + blo(wB.z)*h4.z + bhi(wB.z)*h4.w;
      acc.w += blo(wA.w)*h4.x + bhi(wA.w)*h4.y + blo(wB.w)*h4.z + bhi(wB.w)*h4.w;
    }
    const float ig = sigf(acc.x), fg = sigf(acc.y);
    const float gg = tanhf_(acc.z), og = sigf(acc.w);
    c = fg*c + ig*gg;
    h = og*tanhf_(c);
    __syncthreads();              // everyone done reading vec
    vec[j] = blo(yn);
    vec[256 + j] = h;
    float p[7];
    #pragma unroll
    for (int o = 0; o < 7; ++o) p[o] = h * wh[o];
    #pragma unroll
    for (int o = 0; o < 7; ++o) {
      #pragma unroll
      for (int off = 32; off > 0; off >>= 1) p[o] += __shfl_xor(p[o], off);
    }
    if (lane == 0) {
      #pragma unroll
      for (int o = 0; o < 7; ++o) hd[o][wv] = p[o];
    }
    __syncthreads();              // vec + hd ready
    if (j < DD)
      dout[((size_t)b*TT + t)*DD + j] = bh + hd[j][0] + hd[j][1] + hd[j][2] + hd[j][3];
  }
  dout[917504 + (BB + b)*HH + j] = h;   // h_n[1][b][j]
  dout[925696 + (BB + b)*HH + j] = c;   // c_n[1][b][j]
}

extern "C" void kernel_launch(void* const* d_in, const int* in_sizes, int n_in,
                              void* d_out, int out_size, void* d_ws, size_t ws_size,
                              hipStream_t stream) {
  const float* x     = (const float*)d_in[0];
  const float* Wih0  = (const float*)d_in[1];
  const float* Whh0  = (const float*)d_in[2];
  const float* b0    = (const float*)d_in[3];
  const float* Wih1  = (const float*)d_in[4];
  const float* Whh1  = (const float*)d_in[5];
  const float* b1    = (const float*)d_in[6];
  const float* Whead = (const float*)d_in[7];
  const float* bhead = (const float*)d_in[8];
  char* ws = (char*)d_ws;
  u16*   wpk0 = (u16*)(ws + OFF_W0);
  u16*   wpk1 = (u16*)(ws + OFF_W1);
  float* b0pk = (float*)(ws + OFF_B0);
  float* b1pk = (float*)(ws + OFF_B1);
  u16*   y0   = (u16*)(ws + OFF_Y0);
  float* out  = (float*)d_out;

  pack_kernel<<<3112, 256, 0, stream>>>(Wih0, Whh0, b0, Wih1, Whh1, b1,
                                        wpk0, wpk1, b0pk, b1pk);
  lstm_l0<<<BB, 256, 0, stream>>>(x, (const uint4*)wpk0, (const float4*)b0pk, y0, out);
  lstm_l1<<<BB, 256, 0, stream>>>(y0, (const uint4*)wpk1, (const float4*)b1pk,
                                  Whead, bhead, out);
}

// Round 4
// 62237.915 us; speedup vs baseline: 3.9454x; 3.9454x over previous
//
#include <hip/hip_runtime.h>
#include <hip/hip_bf16.h>

#define TT 8192
#define BB 16
#define HH 256
#define GG 16      // gang blocks per layer
#define NKS0 9     // K=288 (x 0..6, zeros 7..31, h 32..287)
#define NKS1 16    // K=512 (y0 0..255, h1 256..511)
#define ROW0 320   // u16 per batch-row in LDS (40 chunks of 16B)
#define ROW1 512   // 64 chunks

typedef unsigned short u16;
typedef unsigned int   u32;
typedef __attribute__((ext_vector_type(4))) float f32x4;
typedef __attribute__((ext_vector_type(8))) short bf16x8;

union U16X8 { uint4 u; bf16x8 s; };

// ---------------- workspace layout (bytes) ----------------
static const size_t OFF_CNT = 0;        // 2 counters (u32 at +0, +64), 256B reserved
static const size_t OFF_HX0 = 256;      // [2][16][256] u16 = 16384
static const size_t OFF_HX1 = 16640;    // 16384
static const size_t OFF_A0  = 33024;    // 294912 u16 = 589824 B
static const size_t OFF_A1  = 622848;   // 524288 u16 = 1048576 B
static const size_t OFF_Y0  = 1671424;  // [8192][16][256] u16 = 64 MB

__device__ __forceinline__ float sigf(float x){ return 1.0f/(1.0f + __expf(-x)); }
__device__ __forceinline__ float tanhf_(float x){ return 1.0f - 2.0f/(__expf(2.0f*x) + 1.0f); }
__device__ __forceinline__ u16 f2bf(float v){
  union { __hip_bfloat16 b; u16 s; } u; u.b = __float2bfloat16(v); return u.s;
}

// Pack W into MFMA A-fragment order: [g][q][ks][lane][8], lane holds
// A[row=lane&15][k=(lane>>4)*8+i], row_global = q*256+g*16+row.
__global__ __launch_bounds__(256) void pack_frags(
    const float* __restrict__ Wih0, const float* __restrict__ Whh0,
    const float* __restrict__ Wih1, const float* __restrict__ Whh1,
    u16* __restrict__ a0, u16* __restrict__ a1) {
  int idx = blockIdx.x*256 + threadIdx.x;
  const int N0 = GG*4*NKS0*512;   // 294912
  const int N1 = GG*4*NKS1*512;   // 524288
  if (idx < N0) {
    int i = idx;
    int ii = i & 511; int lane = ii >> 3; int e = ii & 7;
    int rest = i >> 9; int ks = rest % NKS0; rest /= NKS0;
    int q = rest & 3; int g = rest >> 2;
    int row = q*256 + g*16 + (lane & 15);
    int k = ks*32 + (lane >> 4)*8 + e;
    float v = 0.0f;
    if (k < 7)                   v = Wih0[row*7 + k];
    else if (k >= 32 && k < 288) v = Whh0[row*256 + (k - 32)];
    a0[i] = f2bf(v);
  } else if (idx < N0 + N1) {
    int i = idx - N0;
    int ii = i & 511; int lane = ii >> 3; int e = ii & 7;
    int rest = i >> 9; int ks = rest & 15; rest >>= 4;
    int q = rest & 3; int g = rest >> 2;
    int row = q*256 + g*16 + (lane & 15);
    int k = ks*32 + (lane >> 4)*8 + e;
    float v = (k < 256) ? Wih1[row*256 + k] : Whh1[row*256 + (k - 256)];
    a1[i] = f2bf(v);
  }
}

__device__ __forceinline__ void gang_barrier(unsigned* cnt, int tid, int t, int* budget) {
  if (tid == 0 && t) {
    unsigned tgt = 16u * (unsigned)t;
    while (__hip_atomic_load(cnt, __ATOMIC_ACQUIRE, __HIP_MEMORY_SCOPE_AGENT) < tgt) {
      __builtin_amdgcn_s_sleep(2);
      if (--(*budget) <= 0) break;   // safety: never hang the bench
    }
  }
  __syncthreads();
}

__device__ __forceinline__ void gang_arrive(unsigned* cnt, int tid) {
  __syncthreads();
  if (tid == 0) {
    __threadfence();
    __hip_atomic_fetch_add(cnt, 1u, __ATOMIC_RELEASE, __HIP_MEMORY_SCOPE_AGENT);
  }
}

// Layer-0 gang: 16 blocks, block g owns units [16g,16g+16).
__global__ __launch_bounds__(256, 1) void gang0(
    const float* __restrict__ x, const u16* __restrict__ afrag,
    const float* __restrict__ bias, u16* __restrict__ hx,
    u16* __restrict__ y0ws, unsigned* __restrict__ cnt,
    float* __restrict__ dout) {
  const int g = blockIdx.x, tid = threadIdx.x;
  const int l = tid & 63, wq = tid >> 6;
  __shared__ __align__(16) u16 hlds[16*ROW0];
  __shared__ float pre[4][16][17];
  uint4* lds4 = (uint4*)hlds;

  uint4 A[NKS0];
  #pragma unroll
  for (int ks = 0; ks < NKS0; ++ks)
    A[ks] = ((const uint4*)afrag)[ ((g*4 + wq)*NKS0 + ks)*64 + l ];
  const int bb_ = l & 15, cq = l >> 4;
  float bias4[4];
  #pragma unroll
  for (int i = 0; i < 4; ++i) bias4[i] = bias[wq*256 + g*16 + cq*4 + i];

  const int pb = tid >> 4, pu = tid & 15;   // pointwise: (batch, unit)
  const int sb = tid >> 4, kg = tid & 15;   // stage: (batch, k-group)
  const int xb = tid >> 3, xj = tid & 7;    // x stage (tid<128)
  float cst = 0.0f, hlast = 0.0f;
  int budget = 6000000;

  { u32* z = (u32*)hlds; for (int i = tid; i < 16*ROW0/2; i += 256) z[i] = 0; }
  __syncthreads();

  for (int t = 0; t < TT; ++t) {
    float xv = 0.0f;                                   // prefetch x_t (no barrier dep)
    if (tid < 128 && xj < 7) xv = x[(size_t)xb*(TT*7) + (size_t)t*7 + xj];

    gang_barrier(cnt, tid, t, &budget);

    // stage h(t): global hx[t&1] -> swizzled LDS (chunks 4..35)
    {
      const uint4* hb = (const uint4*)(hx + ((size_t)(t & 1)*4096 + sb*256 + kg*16));
      uint4 h0 = hb[0], h1 = hb[1];
      lds4[sb*40 + ((4 + 2*kg + 0) ^ (sb & 7))] = h0;
      lds4[sb*40 + ((4 + 2*kg + 1) ^ (sb & 7))] = h1;
    }
    if (tid < 128 && xj < 7)
      hlds[xb*ROW0 + ((xb & 7)*8) + xj] = f2bf(xv);    // chunk 0 ^ (b&7)
    __syncthreads();

    f32x4 acc = { bias4[0], bias4[1], bias4[2], bias4[3] };
    #pragma unroll
    for (int ks = 0; ks < NKS0; ++ks) {
      int c = ks*4 + cq;
      U16X8 a, b;
      a.u = A[ks];
      b.u = lds4[bb_*40 + (c ^ (bb_ & 7))];
      acc = __builtin_amdgcn_mfma_f32_16x16x32_bf16(a.s, b.s, acc, 0, 0, 0);
    }
    #pragma unroll
    for (int i = 0; i < 4; ++i) pre[wq][cq*4 + i][bb_] = acc[i];
    __syncthreads();

    {
      float pi = pre[0][pu][pb], pf = pre[1][pu][pb],
            pg = pre[2][pu][pb], po = pre[3][pu][pb];
      cst = sigf(pf)*cst + sigf(pi)*tanhf_(pg);
      hlast = sigf(po)*tanhf_(cst);
      u16 hb16 = f2bf(hlast);
      hx[(size_t)((t + 1) & 1)*4096 + pb*256 + g*16 + pu] = hb16;
      y0ws[(size_t)t*4096 + pb*256 + g*16 + pu] = hb16;
    }
    gang_arrive(cnt, tid);
  }
  dout[917504 + pb*256 + g*16 + pu] = hlast;   // h_n[0]
  dout[925696 + pb*256 + g*16 + pu] = cst;     // c_n[0]
}

// Layer-1 gang + fused head.
__global__ __launch_bounds__(256, 1) void gang1(
    const u16* __restrict__ y0ws, const u16* __restrict__ afrag,
    const float* __restrict__ bias, u16* __restrict__ hx,
    unsigned* __restrict__ cnt, const float* __restrict__ Whead,
    const float* __restrict__ bhead, float* __restrict__ out) {
  const int g = blockIdx.x, tid = threadIdx.x;
  const int l = tid & 63, wq = tid >> 6;
  __shared__ __align__(16) u16 hlds[16*ROW1];
  __shared__ float pre[4][16][17];
  uint4* lds4 = (uint4*)hlds;

  uint4 A[NKS1];
  #pragma unroll
  for (int ks = 0; ks < NKS1; ++ks)
    A[ks] = ((const uint4*)afrag)[ ((g*4 + wq)*NKS1 + ks)*64 + l ];
  const int bb_ = l & 15, cq = l >> 4;
  float bias4[4];
  #pragma unroll
  for (int i = 0; i < 4; ++i) bias4[i] = bias[wq*256 + g*16 + cq*4 + i];

  const int pb = tid >> 4, pu = tid & 15;
  const int sb = tid >> 4, kg = tid & 15;
  float wh[7], bh[7];
  #pragma unroll
  for (int o = 0; o < 7; ++o) { wh[o] = Whead[o*HH + g*16 + pu]; bh[o] = bhead[o]; }
  float cst = 0.0f, hlast = 0.0f;
  int budget = 6000000;
  __syncthreads();

  for (int t = 0; t < TT; ++t) {
    uint4 py[4];                                        // prefetch y0_t (no barrier dep)
    if (kg < 8) {
      const uint4* yb = (const uint4*)(y0ws + ((size_t)t*4096 + sb*256 + kg*32));
      #pragma unroll
      for (int m = 0; m < 4; ++m) py[m] = yb[m];
    }

    gang_barrier(cnt, tid, t, &budget);

    if (kg < 8) {                                       // y0 -> chunks 0..31
      #pragma unroll
      for (int m = 0; m < 4; ++m)
        lds4[sb*64 + ((4*kg + m) ^ (sb & 7))] = py[m];
    } else {                                            // h1 -> chunks 32..63
      const uint4* hb = (const uint4*)(hx + ((size_t)(t & 1)*4096 + sb*256 + (kg - 8)*32));
      #pragma unroll
      for (int m = 0; m < 4; ++m)
        lds4[sb*64 + ((4*kg + m) ^ (sb & 7))] = hb[m];
    }
    __syncthreads();

    f32x4 acc = { bias4[0], bias4[1], bias4[2], bias4[3] };
    #pragma unroll
    for (int ks = 0; ks < NKS1; ++ks) {
      int c = ks*4 + cq;
      U16X8 a, b;
      a.u = A[ks];
      b.u = lds4[bb_*64 + (c ^ (bb_ & 7))];
      acc = __builtin_amdgcn_mfma_f32_16x16x32_bf16(a.s, b.s, acc, 0, 0, 0);
    }
    #pragma unroll
    for (int i = 0; i < 4; ++i) pre[wq][cq*4 + i][bb_] = acc[i];
    __syncthreads();

    {
      float pi = pre[0][pu][pb], pf = pre[1][pu][pb],
            pg = pre[2][pu][pb], po = pre[3][pu][pb];
      cst = sigf(pf)*cst + sigf(pi)*tanhf_(pg);
      hlast = sigf(po)*tanhf_(cst);
      hx[(size_t)((t + 1) & 1)*4096 + pb*256 + g*16 + pu] = f2bf(hlast);
      // fused head: partial over this block's 16 units, reduce within 16-lane group
      #pragma unroll
      for (int o = 0; o < 7; ++o) {
        float p = hlast * wh[o];
        p += __shfl_xor(p, 1); p += __shfl_xor(p, 2);
        p += __shfl_xor(p, 4); p += __shfl_xor(p, 8);
        if (pu == 0)
          atomicAdd(out + (size_t)pb*(TT*7) + (size_t)t*7 + o,
                    p + (g == 0 ? bh[o] : 0.0f));
      }
    }
    gang_arrive(cnt, tid);
  }
  out[917504 + 4096 + pb*256 + g*16 + pu] = hlast;   // h_n[1]
  out[925696 + 4096 + pb*256 + g*16 + pu] = cst;     // c_n[1]
}

extern "C" void kernel_launch(void* const* d_in, const int* in_sizes, int n_in,
                              void* d_out, int out_size, void* d_ws, size_t ws_size,
                              hipStream_t stream) {
  const float* x     = (const float*)d_in[0];
  const float* Wih0  = (const float*)d_in[1];
  const float* Whh0  = (const float*)d_in[2];
  const float* b0    = (const float*)d_in[3];
  const float* Wih1  = (const float*)d_in[4];
  const float* Whh1  = (const float*)d_in[5];
  const float* b1    = (const float*)d_in[6];
  const float* Whead = (const float*)d_in[7];
  const float* bhead = (const float*)d_in[8];
  char* ws = (char*)d_ws;
  unsigned* cnt0 = (unsigned*)(ws + OFF_CNT);
  unsigned* cnt1 = (unsigned*)(ws + OFF_CNT + 64);
  u16* hx0  = (u16*)(ws + OFF_HX0);
  u16* hx1  = (u16*)(ws + OFF_HX1);
  u16* a0   = (u16*)(ws + OFF_A0);
  u16* a1   = (u16*)(ws + OFF_A1);
  u16* y0ws = (u16*)(ws + OFF_Y0);
  float* out = (float*)d_out;

  // zero counters + h exchange buffers (h(0)=0), and d_out (head accumulates)
  hipMemsetAsync(ws, 0, OFF_A0, stream);
  hipMemsetAsync(d_out, 0, (size_t)933888*sizeof(float), stream);

  pack_frags<<<3200, 256, 0, stream>>>(Wih0, Whh0, Wih1, Whh1, a0, a1);
  gang0<<<GG, 256, 0, stream>>>(x, a0, b0, hx0, y0ws, cnt0, out);
  gang1<<<GG, 256, 0, stream>>>(y0ws, a1, b1, hx1, cnt1, Whead, bhead, out);
}

// Round 5
// 26080.774 us; speedup vs baseline: 9.4150x; 2.3864x over previous
//
#include <hip/hip_runtime.h>
#include <hip/hip_bf16.h>

#define TT 8192
#define BB 16
#define HH 256
#define GG 8       // blocks per layer (16 total)
#define NKS0 9     // K=288: x 0..6, zeros 7..31, h 32..287
#define NKS1 16    // K=512: y0 0..255, h1 256..511
#define ROW0 320   // u16 per batch-row in L0 LDS tile (40 chunks)
#define ROW1 512   // 64 chunks

typedef unsigned short u16;
typedef unsigned int   u32;
typedef __attribute__((ext_vector_type(4))) float f32x4;
typedef __attribute__((ext_vector_type(8))) short bf16x8;

union U16X8 { uint4 u; bf16x8 s; };

// ---------------- workspace layout (bytes) ----------------
static const size_t OFF_SLOT = 0;        // 16 arrival slots, 64 B apart
static const size_t OFF_H0   = 1024;     // u32[4][2048]  h0 ring (bf16 pairs)   32 KB
static const size_t OFF_H1   = 33792;    // u32[2][2048]  h1 double buffer       16 KB
static const size_t OFF_A0   = 50176;    // 294912 u16 A-frags L0
static const size_t OFF_A1   = 640000;   // 524288 u16 A-frags L1
static const size_t OFF_Y1   = 1688576;  // [8192][16][256] u16 y1 history 64 MB

__device__ __forceinline__ float blo(u32 u){ return __uint_as_float(u << 16); }
__device__ __forceinline__ float bhi(u32 u){ return __uint_as_float(u & 0xffff0000u); }
__device__ __forceinline__ float sigf(float x){ return 1.0f/(1.0f + __expf(-x)); }
__device__ __forceinline__ float tanhf_(float x){ return 1.0f - 2.0f/(__expf(2.0f*x) + 1.0f); }
__device__ __forceinline__ u16 f2bf(float v){
  union { __hip_bfloat16 b; u16 s; } u; u.b = __float2bfloat16(v); return u.s;
}

// A-fragments: [g][wq][rt][ks][lane][8]; row = wq*256 + g*32 + rt*16 + (lane&15),
// k = ks*32 + (lane>>4)*8 + e.
__global__ __launch_bounds__(256) void pack_frags(
    const float* __restrict__ Wih0, const float* __restrict__ Whh0,
    const float* __restrict__ Wih1, const float* __restrict__ Whh1,
    u16* __restrict__ a0, u16* __restrict__ a1) {
  int idx = blockIdx.x*256 + threadIdx.x;
  const int N0 = GG*4*2*NKS0*512;   // 294912
  const int N1 = GG*4*2*NKS1*512;   // 524288
  if (idx < N0) {
    int i = idx;
    int ii = i & 511; int lane = ii >> 3; int e = ii & 7;
    int f = i >> 9; int ks = f % NKS0; f /= NKS0;
    int rt = f & 1; f >>= 1; int wq = f & 3; int g = f >> 2;
    int row = wq*256 + g*32 + rt*16 + (lane & 15);
    int k = ks*32 + (lane >> 4)*8 + e;
    float v = 0.0f;
    if (k < 7)                   v = Wih0[row*7 + k];
    else if (k >= 32 && k < 288) v = Whh0[row*256 + (k - 32)];
    a0[i] = f2bf(v);
  } else if (idx < N0 + N1) {
    int i = idx - N0;
    int ii = i & 511; int lane = ii >> 3; int e = ii & 7;
    int f = i >> 9; int ks = f & 15; f >>= 4;
    int rt = f & 1; f >>= 1; int wq = f & 3; int g = f >> 2;
    int row = wq*256 + g*32 + rt*16 + (lane & 15);
    int k = ks*32 + (lane >> 4)*8 + e;
    float v = (k < 256) ? Wih1[row*256 + k] : Whh1[row*256 + (k - 256)];
    a1[i] = f2bf(v);
  }
}

__device__ __forceinline__ void gang_wait(u32* slots_, int i, int tid, int l, int* budget) {
  if (i > 0) {
    if (tid < 64) {
      bool done = false;
      while (!done) {
        u32 v = 0xFFFFFFFFu;
        if (l < 16)
          v = __hip_atomic_load(&slots_[l*16], __ATOMIC_RELAXED, __HIP_MEMORY_SCOPE_AGENT);
        done = (bool)__all((int)(v >= (u32)i));
        if (!done) { __builtin_amdgcn_s_sleep(1); if (--(*budget) <= 0) done = true; }
      }
      // one acquire to invalidate stale L1/L2 lines before data reads
      (void)__hip_atomic_load(&slots_[0], __ATOMIC_ACQUIRE, __HIP_MEMORY_SCOPE_AGENT);
    }
    __syncthreads();
  }
}

__device__ __forceinline__ void gang_arrive(u32* slots_, int gb, int i, int tid) {
  asm volatile("s_waitcnt vmcnt(0)" ::: "memory");  // all my agent stores ACKed
  __syncthreads();                                   // whole block drained
  if (tid == 0)
    __hip_atomic_store(&slots_[gb*16], (u32)(i + 1),
                       __ATOMIC_RELAXED, __HIP_MEMORY_SCOPE_AGENT);
}

// Fused 2-layer pipelined gang: blocks 0..7 = L0 (step t=i), 8..15 = L1 (t=i-2).
__global__ __launch_bounds__(256, 1) void gangs(
    const float* __restrict__ x,
    const u16* __restrict__ a0, const u16* __restrict__ a1,
    const float* __restrict__ b0, const float* __restrict__ b1,
    u32* __restrict__ h0c, u32* __restrict__ h1c,
    u32* __restrict__ slots_, u32* __restrict__ y1ws,
    float* __restrict__ dout) {
  const int gb = blockIdx.x, tid = threadIdx.x;
  const int l = tid & 63, wq = tid >> 6;
  const int bb_ = l & 15, cq = l >> 4;
  const int pb = tid >> 4, pu = tid & 15;   // pointwise: batch, unit-pair
  const int sb = tid >> 4, kg = tid & 15;   // staging: batch, k-group
  __shared__ __align__(16) u16 hlds[16*ROW1];
  __shared__ float pre[4][32][17];
  uint4* lds4 = (uint4*)hlds;
  int budget = 3000000;
  float cst[2] = {0.f, 0.f}, hl[2] = {0.f, 0.f};

  if (gb < GG) {   // ================= LAYER 0 =================
    const int g = gb;
    uint4 A[2][NKS0];
    #pragma unroll
    for (int rt = 0; rt < 2; ++rt)
      #pragma unroll
      for (int ks = 0; ks < NKS0; ++ks)
        A[rt][ks] = ((const uint4*)a0)[ (((g*4 + wq)*2 + rt)*NKS0 + ks)*64 + l ];
    float bias4[2][4];
    #pragma unroll
    for (int rt = 0; rt < 2; ++rt)
      #pragma unroll
      for (int i = 0; i < 4; ++i)
        bias4[rt][i] = b0[wq*256 + g*32 + rt*16 + cq*4 + i];
    const int xb = tid >> 3, xj = tid & 7;
    for (int z = tid; z < 16*ROW0/2; z += 256) ((u32*)hlds)[z] = 0;
    __syncthreads();

    for (int i = 0; i < TT + 2; ++i) {
      const int t = i;
      const bool act = (t < TT);
      float xv = 0.0f;
      if (act && tid < 128 && xj < 7)
        xv = x[(size_t)xb*(TT*7) + (size_t)t*7 + xj];

      gang_wait(slots_, i, tid, l, &budget);

      if (act) {
        {  // stage h0(t) from ring slot (t-1)&3  -> chunks 4..35 (swizzled)
          const uint4* hb = (const uint4*)(h0c + ((t + 3) & 3)*2048 + sb*128 + kg*8);
          uint4 h0v = hb[0], h1v = hb[1];
          lds4[sb*40 + ((4 + 2*kg + 0) ^ (sb & 7))] = h0v;
          lds4[sb*40 + ((4 + 2*kg + 1) ^ (sb & 7))] = h1v;
        }
        if (tid < 128 && xj < 7)
          hlds[xb*ROW0 + ((xb & 7)*8) + xj] = f2bf(xv);
        __syncthreads();

        f32x4 acc[2];
        #pragma unroll
        for (int rt = 0; rt < 2; ++rt)
          acc[rt] = (f32x4){bias4[rt][0], bias4[rt][1], bias4[rt][2], bias4[rt][3]};
        #pragma unroll
        for (int ks = 0; ks < NKS0; ++ks) {
          U16X8 bfr; bfr.u = lds4[bb_*40 + ((ks*4 + cq) ^ (bb_ & 7))];
          U16X8 afr0; afr0.u = A[0][ks];
          U16X8 afr1; afr1.u = A[1][ks];
          acc[0] = __builtin_amdgcn_mfma_f32_16x16x32_bf16(afr0.s, bfr.s, acc[0], 0, 0, 0);
          acc[1] = __builtin_amdgcn_mfma_f32_16x16x32_bf16(afr1.s, bfr.s, acc[1], 0, 0, 0);
        }
        #pragma unroll
        for (int rt = 0; rt < 2; ++rt)
          #pragma unroll
          for (int ii = 0; ii < 4; ++ii)
            pre[wq][rt*16 + cq*4 + ii][bb_] = acc[rt][ii];
        __syncthreads();

        u32 packed;
        {
          #pragma unroll
          for (int e = 0; e < 2; ++e) {
            int u = 2*pu + e;
            float pi = pre[0][u][pb], pf = pre[1][u][pb],
                  pg = pre[2][u][pb], po = pre[3][u][pb];
            cst[e] = sigf(pf)*cst[e] + sigf(pi)*tanhf_(pg);
            hl[e]  = sigf(po)*tanhf_(cst[e]);
          }
          packed = (u32)f2bf(hl[0]) | ((u32)f2bf(hl[1]) << 16);
        }
        __hip_atomic_store(&h0c[(t & 3)*2048 + pb*128 + g*16 + pu], packed,
                           __ATOMIC_RELAXED, __HIP_MEMORY_SCOPE_AGENT);
      }
      gang_arrive(slots_, gb, i, tid);
    }
    #pragma unroll
    for (int e = 0; e < 2; ++e) {
      dout[917504 + pb*256 + g*32 + 2*pu + e] = hl[e];   // h_n[0]
      dout[925696 + pb*256 + g*32 + 2*pu + e] = cst[e];  // c_n[0]
    }
  } else {         // ================= LAYER 1 =================
    const int g = gb - GG;
    uint4 A[2][NKS1];
    #pragma unroll
    for (int rt = 0; rt < 2; ++rt)
      #pragma unroll
      for (int ks = 0; ks < NKS1; ++ks)
        A[rt][ks] = ((const uint4*)a1)[ (((g*4 + wq)*2 + rt)*NKS1 + ks)*64 + l ];
    float bias4[2][4];
    #pragma unroll
    for (int rt = 0; rt < 2; ++rt)
      #pragma unroll
      for (int i = 0; i < 4; ++i)
        bias4[rt][i] = b1[wq*256 + g*32 + rt*16 + cq*4 + i];
    __syncthreads();

    for (int i = 0; i < TT + 2; ++i) {
      const int t1 = i - 2;
      const bool act = (t1 >= 0);
      uint4 py[4];
      if (act && kg < 8) {   // prefetch y0(t1) = h0 ring slot t1&3 (published at barrier i-1)
        const uint4* yb = (const uint4*)(h0c + (t1 & 3)*2048 + sb*128 + kg*16);
        #pragma unroll
        for (int m = 0; m < 4; ++m) py[m] = yb[m];
      }

      gang_wait(slots_, i, tid, l, &budget);

      if (act) {
        if (kg < 8) {          // y0 -> chunks 0..31
          #pragma unroll
          for (int m = 0; m < 4; ++m)
            lds4[sb*64 + ((4*kg + m) ^ (sb & 7))] = py[m];
        } else {               // h1 -> chunks 32..63
          const uint4* hb = (const uint4*)(h1c + (t1 & 1)*2048 + sb*128 + (kg - 8)*16);
          #pragma unroll
          for (int m = 0; m < 4; ++m)
            lds4[sb*64 + ((4*kg + m) ^ (sb & 7))] = hb[m];
        }
        __syncthreads();

        f32x4 acc[2];
        #pragma unroll
        for (int rt = 0; rt < 2; ++rt)
          acc[rt] = (f32x4){bias4[rt][0], bias4[rt][1], bias4[rt][2], bias4[rt][3]};
        #pragma unroll
        for (int ks = 0; ks < NKS1; ++ks) {
          U16X8 bfr; bfr.u = lds4[bb_*64 + ((ks*4 + cq) ^ (bb_ & 7))];
          U16X8 afr0; afr0.u = A[0][ks];
          U16X8 afr1; afr1.u = A[1][ks];
          acc[0] = __builtin_amdgcn_mfma_f32_16x16x32_bf16(afr0.s, bfr.s, acc[0], 0, 0, 0);
          acc[1] = __builtin_amdgcn_mfma_f32_16x16x32_bf16(afr1.s, bfr.s, acc[1], 0, 0, 0);
        }
        #pragma unroll
        for (int rt = 0; rt < 2; ++rt)
          #pragma unroll
          for (int ii = 0; ii < 4; ++ii)
            pre[wq][rt*16 + cq*4 + ii][bb_] = acc[rt][ii];
        __syncthreads();

        u32 packed;
        {
          #pragma unroll
          for (int e = 0; e < 2; ++e) {
            int u = 2*pu + e;
            float pi = pre[0][u][pb], pf = pre[1][u][pb],
                  pg = pre[2][u][pb], po = pre[3][u][pb];
            cst[e] = sigf(pf)*cst[e] + sigf(pi)*tanhf_(pg);
            hl[e]  = sigf(po)*tanhf_(cst[e]);
          }
          packed = (u32)f2bf(hl[0]) | ((u32)f2bf(hl[1]) << 16);
        }
        __hip_atomic_store(&h1c[((t1 + 1) & 1)*2048 + pb*128 + g*16 + pu], packed,
                           __ATOMIC_RELAXED, __HIP_MEMORY_SCOPE_AGENT);
        y1ws[(size_t)t1*2048 + pb*128 + g*16 + pu] = packed;   // plain store (kernel-end flush)
      }
      gang_arrive(slots_, gb, i, tid);
    }
    #pragma unroll
    for (int e = 0; e < 2; ++e) {
      dout[917504 + 4096 + pb*256 + g*32 + 2*pu + e] = hl[e];   // h_n[1]
      dout[925696 + 4096 + pb*256 + g*32 + 2*pu + e] = cst[e];  // c_n[1]
    }
  }
}

// Epilogue head: out[b][t][:] = y1[t][b][:] @ Whead^T + bhead.  Thread per (t,b).
__global__ __launch_bounds__(256) void head_kernel(
    const u16* __restrict__ y1, const float* __restrict__ Wh,
    const float* __restrict__ bh, float* __restrict__ out) {
  __shared__ float wt[256][8];
  const int tid = threadIdx.x;
  for (int idx = tid; idx < 2048; idx += 256) {
    int j = idx >> 3, o = idx & 7;
    wt[j][o] = (o < 7) ? Wh[o*256 + j] : 0.0f;
  }
  __syncthreads();
  const int gidx = blockIdx.x*256 + tid;
  const int t = gidx >> 4, b = gidx & 15;
  const uint4* row = (const uint4*)(y1 + (size_t)t*4096 + b*256);
  float4 a03 = {0,0,0,0}, a47 = {0,0,0,0};
  #pragma unroll 4
  for (int jj = 0; jj < 32; ++jj) {
    uint4 v = row[jj];
    u32 ws_[4] = {v.x, v.y, v.z, v.w};
    #pragma unroll
    for (int m = 0; m < 4; ++m) {
      int j = jj*8 + 2*m;
      float h0 = blo(ws_[m]), h1 = bhi(ws_[m]);
      float4 w00 = *(const float4*)&wt[j][0],   w01 = *(const float4*)&wt[j][4];
      float4 w10 = *(const float4*)&wt[j+1][0], w11 = *(const float4*)&wt[j+1][4];
      a03.x += h0*w00.x; a03.y += h0*w00.y; a03.z += h0*w00.z; a03.w += h0*w00.w;
      a47.x += h0*w01.x; a47.y += h0*w01.y; a47.z += h0*w01.z;
      a03.x += h1*w10.x; a03.y += h1*w10.y; a03.z += h1*w10.z; a03.w += h1*w10.w;
      a47.x += h1*w11.x; a47.y += h1*w11.y; a47.z += h1*w11.z;
    }
  }
  const size_t ob = ((size_t)b*TT + t)*7;
  out[ob+0] = a03.x + bh[0]; out[ob+1] = a03.y + bh[1];
  out[ob+2] = a03.z + bh[2]; out[ob+3] = a03.w + bh[3];
  out[ob+4] = a47.x + bh[4]; out[ob+5] = a47.y + bh[5];
  out[ob+6] = a47.z + bh[6];
}

extern "C" void kernel_launch(void* const* d_in, const int* in_sizes, int n_in,
                              void* d_out, int out_size, void* d_ws, size_t ws_size,
                              hipStream_t stream) {
  const float* x     = (const float*)d_in[0];
  const float* Wih0  = (const float*)d_in[1];
  const float* Whh0  = (const float*)d_in[2];
  const float* b0    = (const float*)d_in[3];
  const float* Wih1  = (const float*)d_in[4];
  const float* Whh1  = (const float*)d_in[5];
  const float* b1    = (const float*)d_in[6];
  const float* Whead = (const float*)d_in[7];
  const float* bhead = (const float*)d_in[8];
  char* ws = (char*)d_ws;
  u32* slots = (u32*)(ws + OFF_SLOT);
  u32* h0c   = (u32*)(ws + OFF_H0);
  u32* h1c   = (u32*)(ws + OFF_H1);
  u16* a0    = (u16*)(ws + OFF_A0);
  u16* a1    = (u16*)(ws + OFF_A1);
  u32* y1ws  = (u32*)(ws + OFF_Y1);
  float* out = (float*)d_out;

  hipMemsetAsync(ws, 0, OFF_A0, stream);   // slots + h0 ring + h1 dbuf = 50176 B

  pack_frags<<<3200, 256, 0, stream>>>(Wih0, Whh0, Wih1, Whh1, a0, a1);
  gangs<<<2*GG, 256, 0, stream>>>(x, a0, a1, b0, b1, h0c, h1c, slots, y1ws, out);
  head_kernel<<<(TT*BB)/256, 256, 0, stream>>>((const u16*)y1ws, Whead, bhead, out);
}